// Round 11
// baseline (232.425 us; speedup 1.0000x reference)
//
#include <hip/hip_runtime.h>
#include <hip/hip_bf16.h>
#include <cstdint>
#include <cstddef>

#define H_DIM 1024
#define I_DIM 512
#define E_NUM 32
#define SHARED_I_DIM 1024
#define TOPK 4
#define NGROUP 8
#define TOPKG 4
#define GT 8   // tokens per gate block

typedef __attribute__((ext_vector_type(8))) short bf16x8;
typedef __attribute__((ext_vector_type(4))) float f32x4;
typedef __attribute__((ext_vector_type(8))) unsigned short u16x8;

__device__ inline unsigned short f2bf(float f) {
    __hip_bfloat16 h = __float2bfloat16(f);   // RNE -> v_cvt_pk_bf16_f32
    return *reinterpret_cast<unsigned short*>(&h);
}
__device__ inline float bf2f(unsigned short u) {
    union { unsigned int u; float f; } w;
    w.u = ((unsigned int)u) << 16;
    return w.f;
}

// async global->LDS DMA, 16B per lane. LDS dest = wave-uniform base + lane*16.
__device__ inline void gload16(const void* g, void* lds) {
    __builtin_amdgcn_global_load_lds(
        (const __attribute__((address_space(1))) void*)g,
        (__attribute__((address_space(3))) void*)lds, 16, 0, 0);
}

// ---------------- init ----------------
__global__ void init_kernel(int* cnt) {
    if (threadIdx.x < 64) cnt[threadIdx.x] = 0;
}

// ---------------- fp32 -> bf16 convert (x) ----------------
__global__ void cvt_kernel(const float* __restrict__ src, unsigned short* __restrict__ dst, int n8) {
    int i = blockIdx.x * blockDim.x + threadIdx.x;
    if (i >= n8) return;
    float4 a = *(const float4*)(src + (size_t)i * 8);
    float4 b = *(const float4*)(src + (size_t)i * 8 + 4);
    u16x8 v;
    v[0] = f2bf(a.x); v[1] = f2bf(a.y); v[2] = f2bf(a.z); v[3] = f2bf(a.w);
    v[4] = f2bf(b.x); v[5] = f2bf(b.y); v[6] = f2bf(b.z); v[7] = f2bf(b.w);
    *(u16x8*)(dst + (size_t)i * 8) = v;
}

// ---------------- gating: 8 tokens per block, fp32 exact ----------------
__global__ __launch_bounds__(256) void gate_kernel(const float* __restrict__ x,
                                                   const float* __restrict__ gw,
                                                   float* __restrict__ logits_out) {
    int tb = blockIdx.x;
    int tid = threadIdx.x;
    __shared__ float xs[GT][H_DIM];
    __shared__ float ps[8][GT][E_NUM];
    const float* xsrc = x + (size_t)tb * GT * H_DIM;
    for (int i = tid; i < GT * H_DIM / 4; i += 256)
        ((float4*)&xs[0][0])[i] = ((const float4*)xsrc)[i];
    __syncthreads();
    int e = tid & 31, part = tid >> 5;
    const float* wrow = gw + (size_t)e * H_DIM + part * 128;
    float acc[GT] = {};
    for (int c0 = 0; c0 < 128; c0 += 32) {
        float w[32];
#pragma unroll
        for (int c = 0; c < 32; c++) w[c] = wrow[c0 + c];
#pragma unroll
        for (int t = 0; t < GT; t++) {
#pragma unroll
            for (int c = 0; c < 32; c++)
                acc[t] += w[c] * xs[t][part * 128 + c0 + c];
        }
    }
#pragma unroll
    for (int t = 0; t < GT; t++) ps[part][t][e] = acc[t];
    __syncthreads();
    {
        int t = tid >> 5, ee = tid & 31;
        float s = 0.f;
#pragma unroll
        for (int p = 0; p < 8; p++) s += ps[p][t][ee];
        logits_out[((size_t)tb * GT + t) * E_NUM + ee] = s;
    }
}

// ---------------- selection ----------------
__global__ void select_kernel(const float* __restrict__ logits, const float* __restrict__ gb,
                              int* __restrict__ topk_e, float* __restrict__ topk_w,
                              int* __restrict__ cnt, int T) {
    int t = blockIdx.x * blockDim.x + threadIdx.x;
    if (t >= T) return;
    float scores[E_NUM], sfc[E_NUM];
#pragma unroll
    for (int i = 0; i < E_NUM; i++) {
        float l = logits[(size_t)t * E_NUM + i];
        float s = 1.f / (1.f + expf(-l));
        scores[i] = s;
        sfc[i] = s + gb[i];
    }
    float gs[NGROUP];
#pragma unroll
    for (int g = 0; g < NGROUP; g++) {
        float m1 = -1e30f, m2 = -1e30f;
#pragma unroll
        for (int j = 0; j < 4; j++) {
            float v = sfc[g * 4 + j];
            if (v > m1) { m2 = m1; m1 = v; }
            else if (v > m2) { m2 = v; }
        }
        gs[g] = m1 + m2;
    }
    unsigned gmask = 0;
    for (int r = 0; r < TOPKG; r++) {
        int best = 0; float bv = -1e30f;
#pragma unroll
        for (int g = 0; g < NGROUP; g++)
            if (!((gmask >> g) & 1u) && gs[g] > bv) { bv = gs[g]; best = g; }
        gmask |= 1u << best;
    }
    unsigned cmask = 0;
    int eidx[TOPK]; float ew[TOPK]; float sum = 0.f;
    for (int r = 0; r < TOPK; r++) {
        int best = 0; float bv = -1e30f; float bsc = 0.f;
#pragma unroll
        for (int i = 0; i < E_NUM; i++) {
            float v = ((gmask >> (i >> 2)) & 1u) ? sfc[i] : 0.0f;
            if (!((cmask >> i) & 1u) && v > bv) { bv = v; best = i; bsc = scores[i]; }
        }
        cmask |= 1u << best;
        eidx[r] = best; ew[r] = bsc; sum += bsc;
    }
    float inv = 1.f / (sum + 1e-20f);
#pragma unroll
    for (int k = 0; k < TOPK; k++) {
        topk_e[t * TOPK + k] = eidx[k];
        topk_w[t * TOPK + k] = ew[k] * inv;
        atomicAdd(&cnt[eidx[k]], 1);
    }
}

// ---------------- scan ----------------
__global__ void scan_kernel(const int* __restrict__ cnt, int* __restrict__ off) {
    if (threadIdx.x == 0) {
        int a = 0;
        for (int e = 0; e < E_NUM; e++) { off[e] = a; a += cnt[e]; }
        off[E_NUM] = a;
    }
}

// ---------------- bin ----------------
__global__ void bin_kernel(const int* __restrict__ topk_e, const float* __restrict__ topk_w,
                           const int* __restrict__ off, int* __restrict__ cnt2,
                           int* __restrict__ slot_token, float* __restrict__ slot_w,
                           int* __restrict__ slot_of, int total) {
    int i = blockIdx.x * blockDim.x + threadIdx.x;
    if (i >= total) return;
    int e = topk_e[i];
    float w = topk_w[i];
    int pos = atomicAdd(&cnt2[e], 1);
    int slot = off[e] + pos;
    slot_token[slot] = i >> 2;
    slot_w[slot] = w;
    slot_of[i] = slot;
}

// ---------------- combine ----------------
__global__ __launch_bounds__(256) void combine_kernel(const unsigned short* __restrict__ out_slot,
                                                      const int* __restrict__ slot_of,
                                                      float* __restrict__ out) {
    int t = blockIdx.x;
    int h = threadIdx.x * 4;
    int s0 = slot_of[t * TOPK + 0], s1 = slot_of[t * TOPK + 1];
    int s2 = slot_of[t * TOPK + 2], s3 = slot_of[t * TOPK + 3];
    ushort4 a = *(const ushort4*)(out_slot + (size_t)s0 * H_DIM + h);
    ushort4 b = *(const ushort4*)(out_slot + (size_t)s1 * H_DIM + h);
    ushort4 c = *(const ushort4*)(out_slot + (size_t)s2 * H_DIM + h);
    ushort4 d = *(const ushort4*)(out_slot + (size_t)s3 * H_DIM + h);
    float4 o = *(float4*)(out + (size_t)t * H_DIM + h);
    o.x += bf2f(a.x) + bf2f(b.x) + bf2f(c.x) + bf2f(d.x);
    o.y += bf2f(a.y) + bf2f(b.y) + bf2f(c.y) + bf2f(d.y);
    o.z += bf2f(a.z) + bf2f(b.z) + bf2f(c.z) + bf2f(d.z);
    o.w += bf2f(a.w) + bf2f(b.w) + bf2f(c.w) + bf2f(d.w);
    *(float4*)(out + (size_t)t * H_DIM + h) = o;
}

// ---------------- merged MoE GEMM: 256x64 tile, BK=32, 512 thr ----------------
// global_load_lds staging, 3 LDS buffers, 2-K-step-deep pipeline with COUNTED
// vmcnt (never drained to 0 in steady state):
//   STAGE(it+2) -> vmcnt(2*LPS) -> s_barrier -> compute(it%3) -> lgkm(0) -> s_barrier
// Swizzle via inverse-permuted per-lane GLOBAL source (m173 pattern):
//   A: LDS(r,p16) holds global chunk p^((r>>1)&3); B: p^(r&7).
// B kept fp32 in LDS, converted at fragment read (16 cvt_pk/wave/K-step).
// blockIdx = (e[0..32], itile, mtile); e==32 is the SHARED expert.
template <bool STAGE1>
__global__ __launch_bounds__(512, 2) void moe_gemm(
    const unsigned short* __restrict__ Axr, const unsigned short* __restrict__ Axs,
    const float* __restrict__ B1r_, const float* __restrict__ B2r_,
    const float* __restrict__ B1s_, const float* __restrict__ B2s_,
    void* __restrict__ Dr, void* __restrict__ Ds,
    const int* __restrict__ slot_token, const float* __restrict__ slot_w,
    const int* __restrict__ cnt, const int* __restrict__ off_arr, int T) {
    constexpr bool DUAL = STAGE1;
    int e = blockIdx.x, itile = blockIdx.y, mtile = blockIdx.z;
    bool sh = (e == E_NUM);
    int NI = (STAGE1 && !sh) ? (I_DIM / 64) : 16;
    if (itile >= NI) return;
    int count = sh ? T : cnt[e];
    int base = sh ? 0 : off_arr[e];
    if (mtile * 256 >= count) return;
    const int K = STAGE1 ? H_DIM : (sh ? SHARED_I_DIM : I_DIM);

    __shared__ __align__(16) unsigned short LA[3][256 * 32];   // 48 KB
    __shared__ __align__(16) float LB1[3][64 * 32];            // 24 KB
    __shared__ __align__(16) float LB2[DUAL ? 3 : 1][DUAL ? 64 * 32 : 4];

    int tid = threadIdx.x, lane = tid & 63, wid = tid >> 6;

    // ---- A staging addresses: 2 gload16 per wave, 16 rows each ----
    int r0 = wid * 32 + (lane >> 2);
    int r1 = r0 + 16;
    const unsigned short* Abase = STAGE1 ? Axr : (sh ? Axs : Axr);
    size_t arow0, arow1;
    {
        int am0 = mtile * 256 + r0, am1 = mtile * 256 + r1;
        int amc0 = (am0 < count) ? am0 : 0, amc1 = (am1 < count) ? am1 : 0;
        if constexpr (STAGE1) {
            arow0 = sh ? (size_t)amc0 : (size_t)slot_token[base + amc0];
            arow1 = sh ? (size_t)amc1 : (size_t)slot_token[base + amc1];
        } else {
            arow0 = sh ? (size_t)amc0 : (size_t)(base + amc0);
            arow1 = sh ? (size_t)amc1 : (size_t)(base + amc1);
        }
    }
    const unsigned short* gA0 = Abase + arow0 * K + (((lane & 3) ^ ((r0 >> 1) & 3)) << 3);
    const unsigned short* gA1 = Abase + arow1 * K + (((lane & 3) ^ ((r1 >> 1) & 3)) << 3);
    unsigned short* lA0 = &LA[0][(wid * 32) * 32];
    unsigned short* lA1 = &LA[0][(wid * 32 + 16) * 32];
    const int ABUF = 256 * 32;

    // ---- B staging addresses: 1 gload16 per wave per matrix, 8 rows each ----
    int br = wid * 8 + (lane >> 3);
    int brow = itile * 64 + br;
    int cb = (lane & 7) ^ (br & 7);
    const float* gB1;
    const float* gB2 = nullptr;
    if constexpr (STAGE1) {
        gB1 = (sh ? B1s_ : (B1r_ + (size_t)e * I_DIM * H_DIM)) + (size_t)brow * K + cb * 4;
        gB2 = (sh ? B2s_ : (B2r_ + (size_t)e * I_DIM * H_DIM)) + (size_t)brow * K + cb * 4;
    } else {
        gB1 = (sh ? B1s_ : (B1r_ + (size_t)e * H_DIM * I_DIM)) + (size_t)brow * K + cb * 4;
    }
    float* lB1 = &LB1[0][(wid * 8) * 32];
    float* lB2 = DUAL ? &LB2[0][(wid * 8) * 32] : nullptr;
    const int BBUF = 64 * 32;

    f32x4 acc1[4][2] = {};
    f32x4 acc2[DUAL ? 4 : 1][2] = {};

    int wrow = (wid >> 1) * 64, wcol = (wid & 1) * 32;
    int frow = lane & 15, fch = lane >> 4;

    auto STAGE = [&](int buf, int it) {
        int k0 = it << 5;
        gload16(gA0 + k0, lA0 + buf * ABUF);
        gload16(gA1 + k0, lA1 + buf * ABUF);
        gload16(gB1 + k0, lB1 + buf * BBUF);
        if constexpr (DUAL) gload16(gB2 + k0, lB2 + buf * BBUF);
    };

    auto rdB = [&](const float* Bb, int nf) -> bf16x8 {
        int r = wcol + nf * 16 + frow;
        f32x4 lo = *(const f32x4*)(Bb + r * 32 + ((((fch << 1)) ^ (r & 7)) << 2));
        f32x4 hi = *(const f32x4*)(Bb + r * 32 + ((((fch << 1) + 1) ^ (r & 7)) << 2));
        u16x8 s;
        s[0] = f2bf(lo[0]); s[1] = f2bf(lo[1]); s[2] = f2bf(lo[2]); s[3] = f2bf(lo[3]);
        s[4] = f2bf(hi[0]); s[5] = f2bf(hi[1]); s[6] = f2bf(hi[2]); s[7] = f2bf(hi[3]);
        union { u16x8 u; bf16x8 b; } cvt; cvt.u = s;
        return cvt.b;
    };

    auto compute = [&](int buf) {
        const unsigned short* As_ = &LA[buf][0];
        const float* B1_ = &LB1[buf][0];
        bf16x8 af[4], b1[2], b2[DUAL ? 2 : 1];
#pragma unroll
        for (int nf = 0; nf < 2; nf++) b1[nf] = rdB(B1_, nf);
        if constexpr (DUAL) {
            const float* B2_ = &LB2[buf][0];
#pragma unroll
            for (int nf = 0; nf < 2; nf++) b2[nf] = rdB(B2_, nf);
        }
#pragma unroll
        for (int mf = 0; mf < 4; mf++) {
            int r = wrow + mf * 16 + frow;
            af[mf] = *(const bf16x8*)(As_ + r * 32 + ((fch ^ ((r >> 1) & 3)) << 3));
        }
#pragma unroll
        for (int mf = 0; mf < 4; mf++)
#pragma unroll
            for (int nf = 0; nf < 2; nf++) {
                acc1[mf][nf] = __builtin_amdgcn_mfma_f32_16x16x32_bf16(af[mf], b1[nf], acc1[mf][nf], 0, 0, 0);
                if constexpr (DUAL)
                    acc2[mf][nf] = __builtin_amdgcn_mfma_f32_16x16x32_bf16(af[mf], b2[nf], acc2[mf][nf], 0, 0, 0);
            }
    };

    const int NK = K >> 5;   // >= 16
    STAGE(0, 0);
    STAGE(1, 1);
    for (int it = 0; it < NK; ++it) {
        if (it + 2 < NK) {
            STAGE((it + 2) % 3, it + 2);
            // wait for step-it loads; steps it+1, it+2 stay in flight
            if constexpr (DUAL) asm volatile("s_waitcnt vmcnt(8)" ::: "memory");
            else                asm volatile("s_waitcnt vmcnt(6)" ::: "memory");
        } else if (it + 1 < NK) {
            if constexpr (DUAL) asm volatile("s_waitcnt vmcnt(4)" ::: "memory");
            else                asm volatile("s_waitcnt vmcnt(3)" ::: "memory");
        } else {
            asm volatile("s_waitcnt vmcnt(0)" ::: "memory");
        }
        __builtin_amdgcn_s_barrier();
        __builtin_amdgcn_sched_barrier(0);   // keep LDS reads below the barrier
        compute(it % 3);
        asm volatile("s_waitcnt lgkmcnt(0)" ::: "memory");
        __builtin_amdgcn_s_barrier();        // reads done before buffer reuse
    }

    // ---- epilogue ----
#pragma unroll
    for (int mf = 0; mf < 4; mf++)
#pragma unroll
        for (int nf = 0; nf < 2; nf++)
#pragma unroll
            for (int j = 0; j < 4; j++) {
                int rloc = wrow + mf * 16 + (lane >> 4) * 4 + j;
                int mrow = mtile * 256 + rloc;
                int col = itile * 64 + wcol + nf * 16 + (lane & 15);
                if (mrow >= count) continue;
                if constexpr (STAGE1) {
                    float w = sh ? 1.0f : slot_w[base + mrow];
                    float g = acc1[mf][nf][j];
                    float a = (g / (1.f + __expf(-g))) * acc2[mf][nf][j] * w;
                    if (sh) ((unsigned short*)Ds)[(size_t)mrow * SHARED_I_DIM + col] = f2bf(a);
                    else    ((unsigned short*)Dr)[(size_t)(base + mrow) * I_DIM + col] = f2bf(a);
                } else {
                    if (sh) ((float*)Ds)[(size_t)mrow * H_DIM + col] = acc1[mf][nf][j];
                    else    ((unsigned short*)Dr)[(size_t)(base + mrow) * H_DIM + col] = f2bf(acc1[mf][nf][j]);
                }
            }
}

extern "C" void kernel_launch(void* const* d_in, const int* in_sizes, int n_in,
                              void* d_out, int out_size, void* d_ws, size_t ws_size,
                              hipStream_t stream) {
    const float* x = (const float*)d_in[0];
    const float* gw = (const float*)d_in[1];
    const float* gb = (const float*)d_in[2];
    const float* gate_proj = (const float*)d_in[3];
    const float* up_proj = (const float*)d_in[4];
    const float* down_proj = (const float*)d_in[5];
    const float* sgw = (const float*)d_in[6];
    const float* suw = (const float*)d_in[7];
    const float* sdw = (const float*)d_in[8];
    float* out = (float*)d_out;

    const int T = in_sizes[0] / H_DIM;       // 2048
    const int total_slots = T * TOPK;        // 8192

    char* ws = (char*)d_ws;
    int* cnt = (int*)ws;                     // 32
    int* cnt2 = cnt + 32;                    // 32
    int* off = cnt + 64;                     // 33
    int* topk_e = cnt + 128;
    float* topk_w = (float*)(topk_e + total_slots);
    int* slot_token = (int*)(topk_w + total_slots);
    float* slot_w = (float*)(slot_token + total_slots);
    int* slot_of = (int*)(slot_w + total_slots);
    float* logits = (float*)(slot_of + total_slots);              // T*32 f32
    unsigned short* x_bf = (unsigned short*)(logits + (size_t)T * E_NUM);
    unsigned short* act_r = x_bf + (size_t)T * H_DIM;             // (slots+256) x I
    unsigned short* act_s = act_r + (size_t)(total_slots + 256) * I_DIM;   // T x SHARED_I
    unsigned short* out_slot = act_s + (size_t)T * SHARED_I_DIM;  // (slots+256) x H

    hipLaunchKernelGGL(init_kernel, dim3(1), dim3(64), 0, stream, cnt);
    hipLaunchKernelGGL(cvt_kernel, dim3((T * H_DIM / 8 + 255) / 256), dim3(256), 0, stream,
                       x, x_bf, T * H_DIM / 8);
    hipLaunchKernelGGL(gate_kernel, dim3(T / GT), dim3(256), 0, stream, x, gw, logits);
    hipLaunchKernelGGL(select_kernel, dim3((T + 255) / 256), dim3(256), 0, stream,
                       logits, gb, topk_e, topk_w, cnt, T);
    hipLaunchKernelGGL(scan_kernel, dim3(1), dim3(1), 0, stream, cnt, off);
    hipLaunchKernelGGL(bin_kernel, dim3((total_slots + 255) / 256), dim3(256), 0, stream,
                       topk_e, topk_w, off, cnt2, slot_token, slot_w, slot_of, total_slots);

    // stage 1 (routed + shared merged): act_r / act_s
    hipLaunchKernelGGL((moe_gemm<true>), dim3(E_NUM + 1, 16, 16), dim3(512), 0, stream,
                       x_bf, (const unsigned short*)nullptr,
                       gate_proj, up_proj, sgw, suw,
                       (void*)act_r, (void*)act_s,
                       slot_token, slot_w, cnt, off, T);

    // stage 2 (routed + shared merged): out_slot (bf16) / out (fp32, once per (t,h))
    hipLaunchKernelGGL((moe_gemm<false>), dim3(E_NUM + 1, 16, 16), dim3(512), 0, stream,
                       act_r, act_s,
                       down_proj, (const float*)nullptr, sdw, (const float*)nullptr,
                       (void*)out_slot, (void*)out,
                       slot_token, slot_w, cnt, off, T);

    // combine: out[t] += sum of the token's 4 routed slot rows
    hipLaunchKernelGGL(combine_kernel, dim3(T), dim3(256), 0, stream, out_slot, slot_of, out);
}

// Round 12
// 225.850 us; speedup vs baseline: 1.0291x; 1.0291x over previous
//
#include <hip/hip_runtime.h>
#include <hip/hip_bf16.h>
#include <cstdint>
#include <cstddef>

#define H_DIM 1024
#define I_DIM 512
#define E_NUM 32
#define SHARED_I_DIM 1024
#define TOPK 4
#define NGROUP 8
#define TOPKG 4
#define GT 8   // tokens per gate block

typedef __attribute__((ext_vector_type(8))) short bf16x8;
typedef __attribute__((ext_vector_type(4))) float f32x4;
typedef __attribute__((ext_vector_type(8))) unsigned short u16x8;

__device__ inline unsigned short f2bf(float f) {
    __hip_bfloat16 h = __float2bfloat16(f);   // RNE -> v_cvt_pk_bf16_f32
    return *reinterpret_cast<unsigned short*>(&h);
}
__device__ inline float bf2f(unsigned short u) {
    union { unsigned int u; float f; } w;
    w.u = ((unsigned int)u) << 16;
    return w.f;
}

// LDS offset (shorts) for [rows][32] bf16 tile, 16B chunks.
// 64B rows: bank phase repeats every 2 rows -> swizzle must use (row>>1).
// chunk ^ ((row>>1)&3) leaves only the free 2-way aliasing (rows 8 apart).
__device__ inline int laddr(int row, int chunk) {
    return row * 32 + ((chunk ^ ((row >> 1) & 3)) << 3);
}

// ---------------- init ----------------
__global__ void init_kernel(int* cnt) {
    if (threadIdx.x < 64) cnt[threadIdx.x] = 0;
}

// ---------------- fp32 -> bf16 convert (x) ----------------
__global__ void cvt_kernel(const float* __restrict__ src, unsigned short* __restrict__ dst, int n8) {
    int i = blockIdx.x * blockDim.x + threadIdx.x;
    if (i >= n8) return;
    float4 a = *(const float4*)(src + (size_t)i * 8);
    float4 b = *(const float4*)(src + (size_t)i * 8 + 4);
    u16x8 v;
    v[0] = f2bf(a.x); v[1] = f2bf(a.y); v[2] = f2bf(a.z); v[3] = f2bf(a.w);
    v[4] = f2bf(b.x); v[5] = f2bf(b.y); v[6] = f2bf(b.z); v[7] = f2bf(b.w);
    *(u16x8*)(dst + (size_t)i * 8) = v;
}

// ---------------- gating: 8 tokens per block, fp32 exact ----------------
__global__ __launch_bounds__(256) void gate_kernel(const float* __restrict__ x,
                                                   const float* __restrict__ gw,
                                                   float* __restrict__ logits_out) {
    int tb = blockIdx.x;
    int tid = threadIdx.x;
    __shared__ float xs[GT][H_DIM];
    __shared__ float ps[8][GT][E_NUM];
    const float* xsrc = x + (size_t)tb * GT * H_DIM;
    for (int i = tid; i < GT * H_DIM / 4; i += 256)
        ((float4*)&xs[0][0])[i] = ((const float4*)xsrc)[i];
    __syncthreads();
    int e = tid & 31, part = tid >> 5;
    const float* wrow = gw + (size_t)e * H_DIM + part * 128;
    float acc[GT] = {};
    for (int c0 = 0; c0 < 128; c0 += 32) {
        float w[32];
#pragma unroll
        for (int c = 0; c < 32; c++) w[c] = wrow[c0 + c];
#pragma unroll
        for (int t = 0; t < GT; t++) {
#pragma unroll
            for (int c = 0; c < 32; c++)
                acc[t] += w[c] * xs[t][part * 128 + c0 + c];
        }
    }
#pragma unroll
    for (int t = 0; t < GT; t++) ps[part][t][e] = acc[t];
    __syncthreads();
    {
        int t = tid >> 5, ee = tid & 31;
        float s = 0.f;
#pragma unroll
        for (int p = 0; p < 8; p++) s += ps[p][t][ee];
        logits_out[((size_t)tb * GT + t) * E_NUM + ee] = s;
    }
}

// ---------------- selection ----------------
__global__ void select_kernel(const float* __restrict__ logits, const float* __restrict__ gb,
                              int* __restrict__ topk_e, float* __restrict__ topk_w,
                              int* __restrict__ cnt, int T) {
    int t = blockIdx.x * blockDim.x + threadIdx.x;
    if (t >= T) return;
    float scores[E_NUM], sfc[E_NUM];
#pragma unroll
    for (int i = 0; i < E_NUM; i++) {
        float l = logits[(size_t)t * E_NUM + i];
        float s = 1.f / (1.f + expf(-l));
        scores[i] = s;
        sfc[i] = s + gb[i];
    }
    float gs[NGROUP];
#pragma unroll
    for (int g = 0; g < NGROUP; g++) {
        float m1 = -1e30f, m2 = -1e30f;
#pragma unroll
        for (int j = 0; j < 4; j++) {
            float v = sfc[g * 4 + j];
            if (v > m1) { m2 = m1; m1 = v; }
            else if (v > m2) { m2 = v; }
        }
        gs[g] = m1 + m2;
    }
    unsigned gmask = 0;
    for (int r = 0; r < TOPKG; r++) {
        int best = 0; float bv = -1e30f;
#pragma unroll
        for (int g = 0; g < NGROUP; g++)
            if (!((gmask >> g) & 1u) && gs[g] > bv) { bv = gs[g]; best = g; }
        gmask |= 1u << best;
    }
    unsigned cmask = 0;
    int eidx[TOPK]; float ew[TOPK]; float sum = 0.f;
    for (int r = 0; r < TOPK; r++) {
        int best = 0; float bv = -1e30f; float bsc = 0.f;
#pragma unroll
        for (int i = 0; i < E_NUM; i++) {
            float v = ((gmask >> (i >> 2)) & 1u) ? sfc[i] : 0.0f;
            if (!((cmask >> i) & 1u) && v > bv) { bv = v; best = i; bsc = scores[i]; }
        }
        cmask |= 1u << best;
        eidx[r] = best; ew[r] = bsc; sum += bsc;
    }
    float inv = 1.f / (sum + 1e-20f);
#pragma unroll
    for (int k = 0; k < TOPK; k++) {
        topk_e[t * TOPK + k] = eidx[k];
        topk_w[t * TOPK + k] = ew[k] * inv;
        atomicAdd(&cnt[eidx[k]], 1);
    }
}

// ---------------- scan ----------------
__global__ void scan_kernel(const int* __restrict__ cnt, int* __restrict__ off) {
    if (threadIdx.x == 0) {
        int a = 0;
        for (int e = 0; e < E_NUM; e++) { off[e] = a; a += cnt[e]; }
        off[E_NUM] = a;
    }
}

// ---------------- bin ----------------
__global__ void bin_kernel(const int* __restrict__ topk_e, const float* __restrict__ topk_w,
                           const int* __restrict__ off, int* __restrict__ cnt2,
                           int* __restrict__ slot_token, float* __restrict__ slot_w,
                           int* __restrict__ slot_of, int total) {
    int i = blockIdx.x * blockDim.x + threadIdx.x;
    if (i >= total) return;
    int e = topk_e[i];
    float w = topk_w[i];
    int pos = atomicAdd(&cnt2[e], 1);
    int slot = off[e] + pos;
    slot_token[slot] = i >> 2;
    slot_w[slot] = w;
    slot_of[i] = slot;
}

// ---------------- combine ----------------
__global__ __launch_bounds__(256) void combine_kernel(const unsigned short* __restrict__ out_slot,
                                                      const int* __restrict__ slot_of,
                                                      float* __restrict__ out) {
    int t = blockIdx.x;
    int h = threadIdx.x * 4;
    int s0 = slot_of[t * TOPK + 0], s1 = slot_of[t * TOPK + 1];
    int s2 = slot_of[t * TOPK + 2], s3 = slot_of[t * TOPK + 3];
    ushort4 a = *(const ushort4*)(out_slot + (size_t)s0 * H_DIM + h);
    ushort4 b = *(const ushort4*)(out_slot + (size_t)s1 * H_DIM + h);
    ushort4 c = *(const ushort4*)(out_slot + (size_t)s2 * H_DIM + h);
    ushort4 d = *(const ushort4*)(out_slot + (size_t)s3 * H_DIM + h);
    float4 o = *(float4*)(out + (size_t)t * H_DIM + h);
    o.x += bf2f(a.x) + bf2f(b.x) + bf2f(c.x) + bf2f(d.x);
    o.y += bf2f(a.y) + bf2f(b.y) + bf2f(c.y) + bf2f(d.y);
    o.z += bf2f(a.z) + bf2f(b.z) + bf2f(c.z) + bf2f(d.z);
    o.w += bf2f(a.w) + bf2f(b.w) + bf2f(c.w) + bf2f(d.w);
    *(float4*)(out + (size_t)t * H_DIM + h) = o;
}

// ---------------- 64x64 MFMA GEMM, BK=32, 256 threads, HIGH OCCUPANCY ---------
// LDS 24KB (dual) / 16KB (single) -> 5-6 blocks/CU: independent blocks'
// barrier phases interleave, hiding HBM latency (rounds 6-11 all ran 1
// block/CU lockstep and capped at ~12 GB/s/CU regardless of schedule).
// Round-6 proven pipeline: reg 2-deep prefetch -> LDS dbuf -> __syncthreads.
// 4 waves: 2 wave-rows x 2 wave-cols; MF=2, NF=2.
// ROUTED: blockIdx = (e, itile, mtile)  [e fastest: live blocks spread]
// MODE 0: dst = bf16( silu(g)*u*w )   (DUAL)
// MODE 1: dst(float) = acc
// MODE 3: dst = bf16(acc) at slot row
template <int MODE, bool DUAL, bool ROUTED, bool AGATHER>
__global__ __launch_bounds__(256, 2) void gemm_kernel(
    const unsigned short* __restrict__ A, const float* __restrict__ B1,
    const float* __restrict__ B2, size_t bstride,
    void* __restrict__ Dst, int ldD,
    const int* __restrict__ slot_token, const float* __restrict__ slot_w,
    const int* __restrict__ cnt, const int* __restrict__ off_arr, int K, int Mtot) {
    static_assert(MODE != 0 || DUAL, "MODE0 requires DUAL");

    int itile, mtile, e;
    if constexpr (ROUTED) { e = blockIdx.x; itile = blockIdx.y; mtile = blockIdx.z; }
    else                  { itile = blockIdx.x; mtile = blockIdx.y; e = 0; }
    int count = Mtot, base = 0;
    if (ROUTED) {
        count = cnt[e];
        base = off_arr[e];
        if (mtile * 64 >= count) return;
    }

    __shared__ __align__(16) unsigned short As[2][64 * 32];    // 8 KB
    __shared__ __align__(16) unsigned short Bs1[2][64 * 32];   // 8 KB
    __shared__ __align__(16) unsigned short Bs2[2][DUAL ? 64 * 32 : 8];

    int tid = threadIdx.x;
    int srow = tid >> 2, sch = tid & 3;   // 4 threads/row, 1 16B chunk each

    int am = mtile * 64 + srow;
    int ar;
    if (AGATHER)      ar = (am < count) ? slot_token[base + am] : 0;
    else if (ROUTED)  ar = base + ((am < count) ? am : 0);
    else              ar = (am < count) ? am : 0;
    const unsigned short* Arow = A + (size_t)ar * K + sch * 8;

    int bn = itile * 64 + srow;
    const float* B1r = B1 + (size_t)e * bstride + (size_t)bn * K + sch * 8;
    const float* B2r = DUAL ? (B2 + (size_t)e * bstride + (size_t)bn * K + sch * 8) : nullptr;

    f32x4 acc1[2][2] = {};
    f32x4 acc2[DUAL ? 2 : 1][2] = {};

    int lane = tid & 63, wid = tid >> 6;
    int wrow = (wid >> 1) * 32, wcol = (wid & 1) * 32;
    int frow = lane & 15, fch = lane >> 4;

    // 2-deep prefetch register sets (statically indexed)
    u16x8 pA0, pA1;
    float4 b1lo0, b1hi0, b1lo1, b1hi1;
    float4 b2lo0, b2hi0, b2lo1, b2hi1;

    auto loadS = [&](u16x8& pA, float4& b1lo, float4& b1hi, float4& b2lo, float4& b2hi, int k0) {
        pA = *(const u16x8*)(Arow + k0);
        b1lo = *(const float4*)(B1r + k0);
        b1hi = *(const float4*)(B1r + k0 + 4);
        if constexpr (DUAL) {
            b2lo = *(const float4*)(B2r + k0);
            b2hi = *(const float4*)(B2r + k0 + 4);
        }
    };
    auto writeS = [&](int buf, u16x8 pA, float4 b1lo, float4 b1hi, float4 b2lo, float4 b2hi) {
        *(u16x8*)(&As[buf][laddr(srow, sch)]) = pA;
        u16x8 s;
        s[0] = f2bf(b1lo.x); s[1] = f2bf(b1lo.y); s[2] = f2bf(b1lo.z); s[3] = f2bf(b1lo.w);
        s[4] = f2bf(b1hi.x); s[5] = f2bf(b1hi.y); s[6] = f2bf(b1hi.z); s[7] = f2bf(b1hi.w);
        *(u16x8*)(&Bs1[buf][laddr(srow, sch)]) = s;
        if constexpr (DUAL) {
            u16x8 s2;
            s2[0] = f2bf(b2lo.x); s2[1] = f2bf(b2lo.y); s2[2] = f2bf(b2lo.z); s2[3] = f2bf(b2lo.w);
            s2[4] = f2bf(b2hi.x); s2[5] = f2bf(b2hi.y); s2[6] = f2bf(b2hi.z); s2[7] = f2bf(b2hi.w);
            *(u16x8*)(&Bs2[buf][laddr(srow, sch)]) = s2;
        }
    };
    auto compute = [&](int buf) {
        bf16x8 af[2], b1[2], b2[DUAL ? 2 : 1];
#pragma unroll
        for (int nf = 0; nf < 2; nf++) {
            int r = wcol + nf * 16 + frow;
            b1[nf] = *(const bf16x8*)(&Bs1[buf][laddr(r, fch)]);
        }
        if constexpr (DUAL) {
#pragma unroll
            for (int nf = 0; nf < 2; nf++) {
                int r = wcol + nf * 16 + frow;
                b2[nf] = *(const bf16x8*)(&Bs2[buf][laddr(r, fch)]);
            }
        }
#pragma unroll
        for (int mf = 0; mf < 2; mf++) {
            int r = wrow + mf * 16 + frow;
            af[mf] = *(const bf16x8*)(&As[buf][laddr(r, fch)]);
        }
#pragma unroll
        for (int mf = 0; mf < 2; mf++)
#pragma unroll
            for (int nf = 0; nf < 2; nf++) {
                acc1[mf][nf] = __builtin_amdgcn_mfma_f32_16x16x32_bf16(af[mf], b1[nf], acc1[mf][nf], 0, 0, 0);
                if constexpr (DUAL)
                    acc2[mf][nf] = __builtin_amdgcn_mfma_f32_16x16x32_bf16(af[mf], b2[nf], acc2[mf][nf], 0, 0, 0);
            }
    };

    const int NK = K >> 5;   // 32 or 16 (even)
    loadS(pA0, b1lo0, b1hi0, b2lo0, b2hi0, 0);
    loadS(pA1, b1lo1, b1hi1, b2lo1, b2hi1, 32);
    writeS(0, pA0, b1lo0, b1hi0, b2lo0, b2hi0);
    loadS(pA0, b1lo0, b1hi0, b2lo0, b2hi0, 64);
    __syncthreads();                               // buf0 ready
    for (int it = 0; it < NK; it += 2) {
        writeS(1, pA1, b1lo1, b1hi1, b2lo1, b2hi1);
        if (it + 3 < NK) loadS(pA1, b1lo1, b1hi1, b2lo1, b2hi1, (it + 3) << 5);
        compute(0);
        __syncthreads();                           // buf1 ready, buf0 free
        if (it + 2 < NK) {
            writeS(0, pA0, b1lo0, b1hi0, b2lo0, b2hi0);
            if (it + 4 < NK) loadS(pA0, b1lo0, b1hi0, b2lo0, b2hi0, (it + 4) << 5);
        }
        compute(1);
        if (it + 2 < NK) __syncthreads();          // buf0 ready, buf1 free
    }

    // ---- epilogue ----
#pragma unroll
    for (int mf = 0; mf < 2; mf++)
#pragma unroll
        for (int nf = 0; nf < 2; nf++)
#pragma unroll
            for (int j = 0; j < 4; j++) {
                int rloc = wrow + mf * 16 + (lane >> 4) * 4 + j;
                int mrow = mtile * 64 + rloc;
                int col = itile * 64 + wcol + nf * 16 + (lane & 15);
                if (mrow >= count) continue;
                if constexpr (MODE == 0) {
                    float w = ROUTED ? slot_w[base + mrow] : 1.0f;
                    float g = acc1[mf][nf][j];
                    float a = (g / (1.f + __expf(-g))) * acc2[mf][nf][j] * w;
                    ((unsigned short*)Dst)[(size_t)(base + mrow) * ldD + col] = f2bf(a);
                } else if constexpr (MODE == 1) {
                    ((float*)Dst)[(size_t)mrow * ldD + col] = acc1[mf][nf][j];
                } else {  // MODE 3: plain bf16 store at slot row
                    ((unsigned short*)Dst)[(size_t)(base + mrow) * ldD + col] = f2bf(acc1[mf][nf][j]);
                }
            }
}

extern "C" void kernel_launch(void* const* d_in, const int* in_sizes, int n_in,
                              void* d_out, int out_size, void* d_ws, size_t ws_size,
                              hipStream_t stream) {
    const float* x = (const float*)d_in[0];
    const float* gw = (const float*)d_in[1];
    const float* gb = (const float*)d_in[2];
    const float* gate_proj = (const float*)d_in[3];
    const float* up_proj = (const float*)d_in[4];
    const float* down_proj = (const float*)d_in[5];
    const float* sgw = (const float*)d_in[6];
    const float* suw = (const float*)d_in[7];
    const float* sdw = (const float*)d_in[8];
    float* out = (float*)d_out;

    const int T = in_sizes[0] / H_DIM;       // 2048
    const int total_slots = T * TOPK;        // 8192

    char* ws = (char*)d_ws;
    int* cnt = (int*)ws;                     // 32
    int* cnt2 = cnt + 32;                    // 32
    int* off = cnt + 64;                     // 33
    int* topk_e = cnt + 128;
    float* topk_w = (float*)(topk_e + total_slots);
    int* slot_token = (int*)(topk_w + total_slots);
    float* slot_w = (float*)(slot_token + total_slots);
    int* slot_of = (int*)(slot_w + total_slots);
    float* logits = (float*)(slot_of + total_slots);              // T*32 f32
    unsigned short* x_bf = (unsigned short*)(logits + (size_t)T * E_NUM);
    unsigned short* act_r = x_bf + (size_t)T * H_DIM;             // (slots+64) x I
    unsigned short* act_s = act_r + (size_t)(total_slots + 64) * I_DIM;    // T x SHARED_I
    unsigned short* out_slot = act_s + (size_t)T * SHARED_I_DIM;  // (slots+64) x H

    hipLaunchKernelGGL(init_kernel, dim3(1), dim3(64), 0, stream, cnt);
    hipLaunchKernelGGL(cvt_kernel, dim3((T * H_DIM / 8 + 255) / 256), dim3(256), 0, stream,
                       x, x_bf, T * H_DIM / 8);
    hipLaunchKernelGGL(gate_kernel, dim3(T / GT), dim3(256), 0, stream, x, gw, logits);
    hipLaunchKernelGGL(select_kernel, dim3((T + 255) / 256), dim3(256), 0, stream,
                       logits, gb, topk_e, topk_w, cnt, T);
    hipLaunchKernelGGL(scan_kernel, dim3(1), dim3(1), 0, stream, cnt, off);
    hipLaunchKernelGGL(bin_kernel, dim3((total_slots + 255) / 256), dim3(256), 0, stream,
                       topk_e, topk_w, off, cnt2, slot_token, slot_w, slot_of, total_slots);

    // routed stage 1: act_r = bf16(silu(x@gateT)*(x@upT)*w); e fastest
    hipLaunchKernelGGL((gemm_kernel<0, true, true, true>),
                       dim3(E_NUM, I_DIM / 64, 32), dim3(256), 0, stream,
                       x_bf, gate_proj, up_proj, (size_t)I_DIM * H_DIM,
                       (void*)act_r, I_DIM, slot_token, slot_w, cnt, off, H_DIM, 0);

    // shared stage 1
    hipLaunchKernelGGL((gemm_kernel<0, true, false, false>),
                       dim3(SHARED_I_DIM / 64, T / 64, 1), dim3(256), 0, stream,
                       x_bf, sgw, suw, (size_t)0,
                       (void*)act_s, SHARED_I_DIM, (const int*)nullptr, (const float*)nullptr,
                       (const int*)nullptr, (const int*)nullptr, H_DIM, T);

    // shared down: fp32 store (covers every (t,h) exactly once)
    hipLaunchKernelGGL((gemm_kernel<1, false, false, false>),
                       dim3(H_DIM / 64, T / 64, 1), dim3(256), 0, stream,
                       act_s, sdw, (const float*)nullptr, (size_t)0,
                       (void*)out, H_DIM, (const int*)nullptr, (const float*)nullptr,
                       (const int*)nullptr, (const int*)nullptr, SHARED_I_DIM, T);

    // routed down: bf16 slot-row store (no atomics); e fastest
    hipLaunchKernelGGL((gemm_kernel<3, false, true, false>),
                       dim3(E_NUM, H_DIM / 64, 32), dim3(256), 0, stream,
                       act_r, down_proj, (const float*)nullptr, (size_t)H_DIM * I_DIM,
                       (void*)out_slot, H_DIM, slot_token, (const float*)nullptr, cnt, off, I_DIM, 0);

    // combine: out[t] += sum of the token's 4 routed slot rows
    hipLaunchKernelGGL(combine_kernel, dim3(T), dim3(256), 0, stream, out_slot, slot_of, out);
}

// Round 13
// 194.969 us; speedup vs baseline: 1.1921x; 1.1584x over previous
//
#include <hip/hip_runtime.h>
#include <hip/hip_bf16.h>
#include <cstdint>
#include <cstddef>

#define H_DIM 1024
#define I_DIM 512
#define E_NUM 32
#define SHARED_I_DIM 1024
#define TOPK 4
#define NGROUP 8
#define TOPKG 4
#define GT 8   // tokens per gate block

typedef __attribute__((ext_vector_type(8))) short bf16x8;
typedef __attribute__((ext_vector_type(4))) float f32x4;
typedef __attribute__((ext_vector_type(8))) unsigned short u16x8;

__device__ inline unsigned short f2bf(float f) {
    __hip_bfloat16 h = __float2bfloat16(f);   // RNE -> v_cvt_pk_bf16_f32
    return *reinterpret_cast<unsigned short*>(&h);
}
__device__ inline float bf2f(unsigned short u) {
    union { unsigned int u; float f; } w;
    w.u = ((unsigned int)u) << 16;
    return w.f;
}

// LDS offset (shorts) for [rows][32] bf16 tile (64B rows), 16B chunks.
// Bank phase repeats every 2 rows -> swizzle on (row>>1); leaves only the
// free 2-way aliasing for 16-row fragment reads.
__device__ inline int laddr(int row, int chunk) {
    return row * 32 + ((chunk ^ ((row >> 1) & 3)) << 3);
}

// ---------------- init ----------------
__global__ void init_kernel(int* cnt) {
    if (threadIdx.x < 64) cnt[threadIdx.x] = 0;
}

// ---------------- fp32 -> bf16 convert (x) ----------------
__global__ void cvt_kernel(const float* __restrict__ src, unsigned short* __restrict__ dst, int n8) {
    int i = blockIdx.x * blockDim.x + threadIdx.x;
    if (i >= n8) return;
    float4 a = *(const float4*)(src + (size_t)i * 8);
    float4 b = *(const float4*)(src + (size_t)i * 8 + 4);
    u16x8 v;
    v[0] = f2bf(a.x); v[1] = f2bf(a.y); v[2] = f2bf(a.z); v[3] = f2bf(a.w);
    v[4] = f2bf(b.x); v[5] = f2bf(b.y); v[6] = f2bf(b.z); v[7] = f2bf(b.w);
    *(u16x8*)(dst + (size_t)i * 8) = v;
}

// ---------------- gating: 8 tokens per block, fp32 exact ----------------
__global__ __launch_bounds__(256) void gate_kernel(const float* __restrict__ x,
                                                   const float* __restrict__ gw,
                                                   float* __restrict__ logits_out) {
    int tb = blockIdx.x;
    int tid = threadIdx.x;
    __shared__ float xs[GT][H_DIM];
    __shared__ float ps[8][GT][E_NUM];
    const float* xsrc = x + (size_t)tb * GT * H_DIM;
    for (int i = tid; i < GT * H_DIM / 4; i += 256)
        ((float4*)&xs[0][0])[i] = ((const float4*)xsrc)[i];
    __syncthreads();
    int e = tid & 31, part = tid >> 5;
    const float* wrow = gw + (size_t)e * H_DIM + part * 128;
    float acc[GT] = {};
    for (int c0 = 0; c0 < 128; c0 += 32) {
        float w[32];
#pragma unroll
        for (int c = 0; c < 32; c++) w[c] = wrow[c0 + c];
#pragma unroll
        for (int t = 0; t < GT; t++) {
#pragma unroll
            for (int c = 0; c < 32; c++)
                acc[t] += w[c] * xs[t][part * 128 + c0 + c];
        }
    }
#pragma unroll
    for (int t = 0; t < GT; t++) ps[part][t][e] = acc[t];
    __syncthreads();
    {
        int t = tid >> 5, ee = tid & 31;
        float s = 0.f;
#pragma unroll
        for (int p = 0; p < 8; p++) s += ps[p][t][ee];
        logits_out[((size_t)tb * GT + t) * E_NUM + ee] = s;
    }
}

// ---------------- selection ----------------
__global__ void select_kernel(const float* __restrict__ logits, const float* __restrict__ gb,
                              int* __restrict__ topk_e, float* __restrict__ topk_w,
                              int* __restrict__ cnt, int T) {
    int t = blockIdx.x * blockDim.x + threadIdx.x;
    if (t >= T) return;
    float scores[E_NUM], sfc[E_NUM];
#pragma unroll
    for (int i = 0; i < E_NUM; i++) {
        float l = logits[(size_t)t * E_NUM + i];
        float s = 1.f / (1.f + expf(-l));
        scores[i] = s;
        sfc[i] = s + gb[i];
    }
    float gs[NGROUP];
#pragma unroll
    for (int g = 0; g < NGROUP; g++) {
        float m1 = -1e30f, m2 = -1e30f;
#pragma unroll
        for (int j = 0; j < 4; j++) {
            float v = sfc[g * 4 + j];
            if (v > m1) { m2 = m1; m1 = v; }
            else if (v > m2) { m2 = v; }
        }
        gs[g] = m1 + m2;
    }
    unsigned gmask = 0;
    for (int r = 0; r < TOPKG; r++) {
        int best = 0; float bv = -1e30f;
#pragma unroll
        for (int g = 0; g < NGROUP; g++)
            if (!((gmask >> g) & 1u) && gs[g] > bv) { bv = gs[g]; best = g; }
        gmask |= 1u << best;
    }
    unsigned cmask = 0;
    int eidx[TOPK]; float ew[TOPK]; float sum = 0.f;
    for (int r = 0; r < TOPK; r++) {
        int best = 0; float bv = -1e30f; float bsc = 0.f;
#pragma unroll
        for (int i = 0; i < E_NUM; i++) {
            float v = ((gmask >> (i >> 2)) & 1u) ? sfc[i] : 0.0f;
            if (!((cmask >> i) & 1u) && v > bv) { bv = v; best = i; bsc = scores[i]; }
        }
        cmask |= 1u << best;
        eidx[r] = best; ew[r] = bsc; sum += bsc;
    }
    float inv = 1.f / (sum + 1e-20f);
#pragma unroll
    for (int k = 0; k < TOPK; k++) {
        topk_e[t * TOPK + k] = eidx[k];
        topk_w[t * TOPK + k] = ew[k] * inv;
        atomicAdd(&cnt[eidx[k]], 1);
    }
}

// ---------------- scan ----------------
__global__ void scan_kernel(const int* __restrict__ cnt, int* __restrict__ off) {
    if (threadIdx.x == 0) {
        int a = 0;
        for (int e = 0; e < E_NUM; e++) { off[e] = a; a += cnt[e]; }
        off[E_NUM] = a;
    }
}

// ---------------- bin ----------------
__global__ void bin_kernel(const int* __restrict__ topk_e, const float* __restrict__ topk_w,
                           const int* __restrict__ off, int* __restrict__ cnt2,
                           int* __restrict__ slot_token, float* __restrict__ slot_w,
                           int* __restrict__ slot_of, int total) {
    int i = blockIdx.x * blockDim.x + threadIdx.x;
    if (i >= total) return;
    int e = topk_e[i];
    float w = topk_w[i];
    int pos = atomicAdd(&cnt2[e], 1);
    int slot = off[e] + pos;
    slot_token[slot] = i >> 2;
    slot_w[slot] = w;
    slot_of[i] = slot;
}

// ---------------- combine ----------------
__global__ __launch_bounds__(256) void combine_kernel(const unsigned short* __restrict__ out_slot,
                                                      const int* __restrict__ slot_of,
                                                      float* __restrict__ out) {
    int t = blockIdx.x;
    int h = threadIdx.x * 4;
    int s0 = slot_of[t * TOPK + 0], s1 = slot_of[t * TOPK + 1];
    int s2 = slot_of[t * TOPK + 2], s3 = slot_of[t * TOPK + 3];
    ushort4 a = *(const ushort4*)(out_slot + (size_t)s0 * H_DIM + h);
    ushort4 b = *(const ushort4*)(out_slot + (size_t)s1 * H_DIM + h);
    ushort4 c = *(const ushort4*)(out_slot + (size_t)s2 * H_DIM + h);
    ushort4 d = *(const ushort4*)(out_slot + (size_t)s3 * H_DIM + h);
    float4 o = *(float4*)(out + (size_t)t * H_DIM + h);
    o.x += bf2f(a.x) + bf2f(b.x) + bf2f(c.x) + bf2f(d.x);
    o.y += bf2f(a.y) + bf2f(b.y) + bf2f(c.y) + bf2f(d.y);
    o.z += bf2f(a.z) + bf2f(b.z) + bf2f(c.z) + bf2f(d.z);
    o.w += bf2f(a.w) + bf2f(b.w) + bf2f(c.w) + bf2f(d.w);
    *(float4*)(out + (size_t)t * H_DIM + h) = o;
}

// ------- merged MoE GEMM: 256x64 tile, BK=32, 512 thr, min weight traffic ------
// blockIdx = (e[0..32], itile, mtile); e==32 is the SHARED expert; merging
// shared tiles into the routed grid fills CUs the routed grid leaves idle.
// Round-6 proven pipeline: 2-deep reg prefetch -> LDS dbuf -> __syncthreads.
// B converted fp32->bf16 at ds_write. LDS: dual 48KB, single 40KB.
// 8 waves: 4 wave-rows (64) x 2 wave-cols (32); MF=4, NF=2.
// STAGE1: act = silu(x@gateT)*(x@upT)*w -> bf16 (act_r routed / act_s shared)
// STAGE2: routed -> bf16 out_slot rows; shared -> fp32 out (once per (t,h))
template <bool STAGE1>
__global__ __launch_bounds__(512, 2) void moe_gemm(
    const unsigned short* __restrict__ Axr, const unsigned short* __restrict__ Axs,
    const float* __restrict__ B1r_, const float* __restrict__ B2r_,
    const float* __restrict__ B1s_, const float* __restrict__ B2s_,
    void* __restrict__ Dr, void* __restrict__ Ds,
    const int* __restrict__ slot_token, const float* __restrict__ slot_w,
    const int* __restrict__ cnt, const int* __restrict__ off_arr, int T) {
    constexpr bool DUAL = STAGE1;
    int e = blockIdx.x, itile = blockIdx.y, mtile = blockIdx.z;
    bool sh = (e == E_NUM);
    int NI = STAGE1 ? (sh ? 16 : 8) : 16;
    if (itile >= NI) return;
    int count = sh ? T : cnt[e];
    int base = sh ? 0 : off_arr[e];
    if (mtile * 256 >= count) return;
    const int K = STAGE1 ? H_DIM : (sh ? SHARED_I_DIM : I_DIM);

    __shared__ __align__(16) unsigned short As[2][256 * 32];    // 32 KB
    __shared__ __align__(16) unsigned short Bs1[2][64 * 32];    // 8 KB
    __shared__ __align__(16) unsigned short Bs2[2][DUAL ? 64 * 32 : 8];

    int tid = threadIdx.x, lane = tid & 63, wid = tid >> 6;

    // ---- A staging: 2 threads/row, 2x16B chunks each ----
    int as_row = tid >> 1, as_c0 = (tid & 1) * 2;
    int am = mtile * 256 + as_row;
    int amc = (am < count) ? am : 0;
    const unsigned short* Abase;
    size_t arow;
    if constexpr (STAGE1) {
        Abase = Axr;
        arow = sh ? (size_t)amc : (size_t)slot_token[base + amc];
    } else {
        Abase = sh ? Axs : Axr;
        arow = sh ? (size_t)amc : (size_t)(base + amc);
    }
    const unsigned short* Ga = Abase + arow * K + as_c0 * 8;

    // ---- B staging: 8 threads/row, 4 floats each -> 8B bf16 ds_write ----
    int bs_row = tid >> 3;
    int brow = itile * 64 + bs_row;
    int bwr = laddr(bs_row, (tid & 7) >> 1) + (tid & 1) * 4;
    const float* Gb1;
    const float* Gb2 = nullptr;
    if constexpr (STAGE1) {
        Gb1 = (sh ? B1s_ : (B1r_ + (size_t)e * (I_DIM * H_DIM))) + (size_t)brow * K + (tid & 7) * 4;
        Gb2 = (sh ? B2s_ : (B2r_ + (size_t)e * (I_DIM * H_DIM))) + (size_t)brow * K + (tid & 7) * 4;
    } else {
        Gb1 = (sh ? B1s_ : (B1r_ + (size_t)e * (H_DIM * I_DIM))) + (size_t)brow * K + (tid & 7) * 4;
    }

    f32x4 acc1[4][2] = {};
    f32x4 acc2[DUAL ? 4 : 1][2] = {};

    int wrow = (wid >> 1) * 64, wcol = (wid & 1) * 32;
    int frow = lane & 15, fch = lane >> 4;

    // 2-deep prefetch sets (all statically indexed)
    u16x8 a00, a01, a10, a11;
    float4 b10, b20, b11, b21;

    auto loadS = [&](u16x8& a0, u16x8& a1, float4& b1v, float4& b2v, int ks) {
        int k0 = ks << 5;
        a0 = *(const u16x8*)(Ga + k0);
        a1 = *(const u16x8*)(Ga + k0 + 8);
        b1v = *(const float4*)(Gb1 + k0);
        if constexpr (DUAL) b2v = *(const float4*)(Gb2 + k0);
    };
    auto writeS = [&](int buf, u16x8 a0, u16x8 a1, float4 b1v, float4 b2v) {
        *(u16x8*)(&As[buf][laddr(as_row, as_c0)]) = a0;
        *(u16x8*)(&As[buf][laddr(as_row, as_c0 + 1)]) = a1;
        ushort4 s;
        s.x = f2bf(b1v.x); s.y = f2bf(b1v.y); s.z = f2bf(b1v.z); s.w = f2bf(b1v.w);
        *(ushort4*)(&Bs1[buf][bwr]) = s;
        if constexpr (DUAL) {
            ushort4 s2;
            s2.x = f2bf(b2v.x); s2.y = f2bf(b2v.y); s2.z = f2bf(b2v.z); s2.w = f2bf(b2v.w);
            *(ushort4*)(&Bs2[buf][bwr]) = s2;
        }
    };
    auto compute = [&](int buf) {
        bf16x8 af[4], b1[2], b2[DUAL ? 2 : 1];
#pragma unroll
        for (int nf = 0; nf < 2; nf++)
            b1[nf] = *(const bf16x8*)(&Bs1[buf][laddr(wcol + nf * 16 + frow, fch)]);
        if constexpr (DUAL) {
#pragma unroll
            for (int nf = 0; nf < 2; nf++)
                b2[nf] = *(const bf16x8*)(&Bs2[buf][laddr(wcol + nf * 16 + frow, fch)]);
        }
#pragma unroll
        for (int mf = 0; mf < 4; mf++)
            af[mf] = *(const bf16x8*)(&As[buf][laddr(wrow + mf * 16 + frow, fch)]);
#pragma unroll
        for (int mf = 0; mf < 4; mf++)
#pragma unroll
            for (int nf = 0; nf < 2; nf++) {
                acc1[mf][nf] = __builtin_amdgcn_mfma_f32_16x16x32_bf16(af[mf], b1[nf], acc1[mf][nf], 0, 0, 0);
                if constexpr (DUAL)
                    acc2[mf][nf] = __builtin_amdgcn_mfma_f32_16x16x32_bf16(af[mf], b2[nf], acc2[mf][nf], 0, 0, 0);
            }
    };

    const int NK = K >> 5;   // 32 or 16 (even)
    loadS(a00, a01, b10, b20, 0);
    loadS(a10, a11, b11, b21, 1);
    writeS(0, a00, a01, b10, b20);
    loadS(a00, a01, b10, b20, 2);
    __syncthreads();                               // buf0 ready
    for (int it = 0; it < NK; it += 2) {
        writeS(1, a10, a11, b11, b21);
        if (it + 3 < NK) loadS(a10, a11, b11, b21, it + 3);
        compute(0);
        __syncthreads();                           // buf1 ready, buf0 free
        if (it + 2 < NK) {
            writeS(0, a00, a01, b10, b20);
            if (it + 4 < NK) loadS(a00, a01, b10, b20, it + 4);
        }
        compute(1);
        if (it + 2 < NK) __syncthreads();          // buf0 ready, buf1 free
    }

    // ---- epilogue ----
#pragma unroll
    for (int mf = 0; mf < 4; mf++)
#pragma unroll
        for (int nf = 0; nf < 2; nf++)
#pragma unroll
            for (int j = 0; j < 4; j++) {
                int rloc = wrow + mf * 16 + (lane >> 4) * 4 + j;
                int mrow = mtile * 256 + rloc;
                int col = itile * 64 + wcol + nf * 16 + (lane & 15);
                if (mrow >= count) continue;
                if constexpr (STAGE1) {
                    float w = sh ? 1.0f : slot_w[base + mrow];
                    float g = acc1[mf][nf][j];
                    float a = (g / (1.f + __expf(-g))) * acc2[mf][nf][j] * w;
                    if (sh) ((unsigned short*)Ds)[(size_t)mrow * SHARED_I_DIM + col] = f2bf(a);
                    else    ((unsigned short*)Dr)[(size_t)(base + mrow) * I_DIM + col] = f2bf(a);
                } else {
                    if (sh) ((float*)Ds)[(size_t)mrow * H_DIM + col] = acc1[mf][nf][j];
                    else    ((unsigned short*)Dr)[(size_t)(base + mrow) * H_DIM + col] = f2bf(acc1[mf][nf][j]);
                }
            }
}

extern "C" void kernel_launch(void* const* d_in, const int* in_sizes, int n_in,
                              void* d_out, int out_size, void* d_ws, size_t ws_size,
                              hipStream_t stream) {
    const float* x = (const float*)d_in[0];
    const float* gw = (const float*)d_in[1];
    const float* gb = (const float*)d_in[2];
    const float* gate_proj = (const float*)d_in[3];
    const float* up_proj = (const float*)d_in[4];
    const float* down_proj = (const float*)d_in[5];
    const float* sgw = (const float*)d_in[6];
    const float* suw = (const float*)d_in[7];
    const float* sdw = (const float*)d_in[8];
    float* out = (float*)d_out;

    const int T = in_sizes[0] / H_DIM;       // 2048
    const int total_slots = T * TOPK;        // 8192

    char* ws = (char*)d_ws;
    int* cnt = (int*)ws;                     // 32
    int* cnt2 = cnt + 32;                    // 32
    int* off = cnt + 64;                     // 33
    int* topk_e = cnt + 128;
    float* topk_w = (float*)(topk_e + total_slots);
    int* slot_token = (int*)(topk_w + total_slots);
    float* slot_w = (float*)(slot_token + total_slots);
    int* slot_of = (int*)(slot_w + total_slots);
    float* logits = (float*)(slot_of + total_slots);              // T*32 f32
    unsigned short* x_bf = (unsigned short*)(logits + (size_t)T * E_NUM);
    unsigned short* act_r = x_bf + (size_t)T * H_DIM;             // (slots+256) x I
    unsigned short* act_s = act_r + (size_t)(total_slots + 256) * I_DIM;   // T x SHARED_I
    unsigned short* out_slot = act_s + (size_t)T * SHARED_I_DIM;  // (slots+256) x H

    hipLaunchKernelGGL(init_kernel, dim3(1), dim3(64), 0, stream, cnt);
    hipLaunchKernelGGL(cvt_kernel, dim3((T * H_DIM / 8 + 255) / 256), dim3(256), 0, stream,
                       x, x_bf, T * H_DIM / 8);
    hipLaunchKernelGGL(gate_kernel, dim3(T / GT), dim3(256), 0, stream, x, gw, logits);
    hipLaunchKernelGGL(select_kernel, dim3((T + 255) / 256), dim3(256), 0, stream,
                       logits, gb, topk_e, topk_w, cnt, T);
    hipLaunchKernelGGL(scan_kernel, dim3(1), dim3(1), 0, stream, cnt, off);
    hipLaunchKernelGGL(bin_kernel, dim3((total_slots + 255) / 256), dim3(256), 0, stream,
                       topk_e, topk_w, off, cnt2, slot_token, slot_w, slot_of, total_slots);

    // stage 1 (routed BM=256 + shared merged): act_r / act_s
    hipLaunchKernelGGL((moe_gemm<true>), dim3(E_NUM + 1, 16, 32), dim3(512), 0, stream,
                       x_bf, (const unsigned short*)nullptr,
                       gate_proj, up_proj, sgw, suw,
                       (void*)act_r, (void*)act_s,
                       slot_token, slot_w, cnt, off, T);

    // stage 2 (routed + shared merged): out_slot (bf16) / out (fp32, once per (t,h))
    hipLaunchKernelGGL((moe_gemm<false>), dim3(E_NUM + 1, 16, 32), dim3(512), 0, stream,
                       act_r, act_s,
                       down_proj, (const float*)nullptr, sdw, (const float*)nullptr,
                       (void*)out_slot, (void*)out,
                       slot_token, slot_w, cnt, off, T);

    // combine: out[t] += sum of the token's 4 routed slot rows
    hipLaunchKernelGGL(combine_kernel, dim3(T), dim3(256), 0, stream, out_slot, slot_of, out);
}